// Round 1
// baseline (552.702 us; speedup 1.0000x reference)
//
#include <hip/hip_runtime.h>

#define HID   256
#define BATCH 8
#define TT    256   // time steps (SEQ-1)
#define SEQL  257
#define VOCAB 29
#define EMB   64

typedef _Float16 f16;
typedef f16  f16x8 __attribute__((ext_vector_type(8)));
typedef float f32x4 __attribute__((ext_vector_type(4)));

__device__ __forceinline__ float fast_tanh(float x) {
    // tanh(x) = 1 - 2/(1+e^{2x});  e^{2x} = 2^{2x*log2(e)}
    float e = exp2f(x * 2.8853900817779268f);
    return 1.0f - 2.0f * __builtin_amdgcn_rcpf(1.0f + e);
}

// C0[t][b][i] = emb[x[b][t]] . W_ih0[i] + b_ih0[i] + b_hh0[i]
__global__ __launch_bounds__(256) void pre0_kernel(
    const int* __restrict__ x, const float* __restrict__ embed,
    const float* __restrict__ Wih0, const float* __restrict__ bih0,
    const float* __restrict__ bhh0, float* __restrict__ C0)
{
    int b  = blockIdx.x & 7;
    int t0 = (blockIdx.x >> 3) * 8;
    int tid = threadIdx.x;
    __shared__ float er[8][EMB];
    for (int idx = tid; idx < 8 * EMB; idx += 256) {
        int tt = idx >> 6, j = idx & 63;
        er[tt][j] = embed[x[b * SEQL + t0 + tt] * EMB + j];
    }
    __syncthreads();
    int i = tid;
    float base = bih0[i] + bhh0[i];
    float acc[8];
#pragma unroll
    for (int tt = 0; tt < 8; ++tt) acc[tt] = base;
    const float* wr = Wih0 + i * EMB;
    for (int j = 0; j < EMB; j += 4) {
        float4 w = *(const float4*)&wr[j];
#pragma unroll
        for (int tt = 0; tt < 8; ++tt) {
            float4 h = *(const float4*)&er[tt][j];
            acc[tt] += h.x * w.x + h.y * w.y + h.z * w.z + h.w * w.w;
        }
    }
#pragma unroll
    for (int tt = 0; tt < 8; ++tt)
        C0[((t0 + tt) * BATCH + b) * HID + i] = acc[tt];
}

// Persistent-weight recurrence: h_t = tanh(C[t] + W * h_{t-1}), one WG per batch.
// 512 threads = 8 waves; wave w owns output cols [w*32, w*32+32).
// W columns live in registers as f16 MFMA B-fragments for all 256 steps.
__global__ __launch_bounds__(512) void rec_kernel(
    const float* __restrict__ W,     // [HID][HID], out[n] = sum_k h[k]*W[n][k]
    const float* __restrict__ C,     // [t][b][i]
    float* __restrict__ Hout)        // [b][t][i]
{
    int b = blockIdx.x;
    int tid = threadIdx.x;
    int wave = tid >> 6, lane = tid & 63;
    int lrow = lane & 15, lkg = lane >> 4;
    __shared__ f16 hbuf[2][HID];
    for (int idx = tid; idx < 2 * HID; idx += 512) ((f16*)hbuf)[idx] = (f16)0.f;

    // B-frag: lane holds B[k = kt*32 + lkg*8 + e][n = wave*32 + ct*16 + lrow]
    //         = W[n][k]
    f16x8 bf[8][2];
#pragma unroll
    for (int kt = 0; kt < 8; ++kt)
#pragma unroll
        for (int ct = 0; ct < 2; ++ct) {
            int n = wave * 32 + ct * 16 + lrow;
            const float* src = W + n * HID + kt * 32 + lkg * 8;
            f16x8 v;
#pragma unroll
            for (int e = 0; e < 8; ++e) v[e] = (f16)src[e];
            bf[kt][ct] = v;
        }
    __syncthreads();

    int cur = 0;
    for (int t = 0; t < TT; ++t) {
        f32x4 acc0 = {0.f, 0.f, 0.f, 0.f}, acc1 = {0.f, 0.f, 0.f, 0.f};
#pragma unroll
        for (int kt = 0; kt < 8; ++kt) {
            f16x8 a;
#pragma unroll
            for (int e = 0; e < 8; ++e) a[e] = (f16)0.f;
            if (lrow == 0)  // A row 0 = h_prev; rows 1..15 zero (M=1)
                a = *(const f16x8*)&hbuf[cur][kt * 32 + lkg * 8];
            acc0 = __builtin_amdgcn_mfma_f32_16x16x32_f16(a, bf[kt][0], acc0, 0, 0, 0);
            acc1 = __builtin_amdgcn_mfma_f32_16x16x32_f16(a, bf[kt][1], acc1, 0, 0, 0);
        }
        int nxt = cur ^ 1;
        if (lane < 16) {   // D row 0 lives in lanes 0..15, reg 0
            int i0 = wave * 32 + lane, i1 = i0 + 16;
            const float* c = C + (t * BATCH + b) * HID;
            float v0 = fast_tanh(acc0[0] + c[i0]);
            float v1 = fast_tanh(acc1[0] + c[i1]);
            hbuf[nxt][i0] = (f16)v0;
            hbuf[nxt][i1] = (f16)v1;
            float* ho = Hout + ((size_t)b * TT + t) * HID;
            ho[i0] = v0;
            ho[i1] = v1;
        }
        cur = nxt;
        __syncthreads();
    }
}

// Out[...] = In[b][t][:] . W[i][:] (+bias0[i]+bias1[i]); K = 256
__global__ __launch_bounds__(256) void gemm256_kernel(
    const float* __restrict__ In, const float* __restrict__ W,
    const float* __restrict__ bias0, const float* __restrict__ bias1,
    float* __restrict__ Out, int tmajor)
{
    int b  = blockIdx.x & 7;
    int t0 = (blockIdx.x >> 3) * 8;
    int tid = threadIdx.x;
    __shared__ float hs[8][HID];
    for (int idx = tid; idx < 8 * HID; idx += 256) {
        int tt = idx >> 8, j = idx & 255;
        hs[tt][j] = In[((size_t)b * TT + t0 + tt) * HID + j];
    }
    __syncthreads();
    int i = tid;
    float base = 0.f;
    if (bias0) base += bias0[i];
    if (bias1) base += bias1[i];
    float acc[8];
#pragma unroll
    for (int tt = 0; tt < 8; ++tt) acc[tt] = base;
    const float* wr = W + i * HID;
    for (int j = 0; j < HID; j += 4) {
        float4 w = *(const float4*)&wr[j];
#pragma unroll
        for (int tt = 0; tt < 8; ++tt) {
            float4 h = *(const float4*)&hs[tt][j];
            acc[tt] += h.x * w.x + h.y * w.y + h.z * w.z + h.w * w.w;
        }
    }
#pragma unroll
    for (int tt = 0; tt < 8; ++tt) {
        int t = t0 + tt;
        size_t o = tmajor ? ((size_t)(t * BATCH + b) * HID + i)
                          : (((size_t)b * TT + t) * HID + i);
        Out[o] = acc[tt];
    }
}

// Per (b,t): scores s<t = v.tanh(q_t + k_s); softmax; ctx = alpha @ Hs;
// out = [h_t, ctx] @ Wfc^T + bfc
__global__ __launch_bounds__(256) void attn_kernel(
    const float* __restrict__ q, const float* __restrict__ k,
    const float* __restrict__ vvec, const float* __restrict__ Hs,
    const float* __restrict__ Wfc, const float* __restrict__ bfc,
    float* __restrict__ out)
{
    int b = blockIdx.x >> 8;
    int t = blockIdx.x & 255;
    int tid = threadIdx.x;
    int wave = tid >> 6, lane = tid & 63;
    __shared__ float qs[HID], vs[HID], alpha[HID], cvec[2 * HID];
    __shared__ float redm[4], reds[4];
    qs[tid] = q[((size_t)b * TT + t) * HID + tid];
    vs[tid] = vvec[tid];
    __syncthreads();

    float sc = -1e30f;
    if (tid < t) {
        const float* kr = k + ((size_t)b * TT + tid) * HID;
        float a = 0.f;
        for (int j = 0; j < HID; j += 4) {
            float4 kv = *(const float4*)&kr[j];
            float4 qv = *(const float4*)&qs[j];
            float4 vv = *(const float4*)&vs[j];
            a += vv.x * fast_tanh(qv.x + kv.x);
            a += vv.y * fast_tanh(qv.y + kv.y);
            a += vv.z * fast_tanh(qv.z + kv.z);
            a += vv.w * fast_tanh(qv.w + kv.w);
        }
        sc = a;
    }
    // block max
    float m = sc;
#pragma unroll
    for (int off = 32; off; off >>= 1) m = fmaxf(m, __shfl_down(m, off));
    if (lane == 0) redm[wave] = m;
    __syncthreads();
    m = fmaxf(fmaxf(redm[0], redm[1]), fmaxf(redm[2], redm[3]));
    float e = (tid < t) ? exp2f((sc - m) * 1.4426950408889634f) : 0.f;
    float z = e;
#pragma unroll
    for (int off = 32; off; off >>= 1) z += __shfl_down(z, off);
    if (lane == 0) reds[wave] = z;
    __syncthreads();
    z = reds[0] + reds[1] + reds[2] + reds[3];
    alpha[tid] = (t == 0) ? 0.f : e * __builtin_amdgcn_rcpf(z);
    __syncthreads();

    float c = 0.f;
    const float* hb = Hs + (size_t)b * TT * HID;
    int tc = (t + 3) & ~3;
    for (int s = 0; s < tc; s += 4) {
        float4 av = *(const float4*)&alpha[s];
        c += av.x * hb[(s + 0) * HID + tid];
        c += av.y * hb[(s + 1) * HID + tid];
        c += av.z * hb[(s + 2) * HID + tid];
        c += av.w * hb[(s + 3) * HID + tid];
    }
    cvec[tid] = hb[(size_t)t * HID + tid];
    cvec[HID + tid] = c;
    __syncthreads();

    if (tid < VOCAB * 8) {
        int o = tid >> 3, p = tid & 7;
        const float* wr = Wfc + o * 2 * HID + p * 64;
        const float* cv = &cvec[p * 64];
        float a = 0.f;
        for (int j = 0; j < 64; j += 4) {
            float4 w  = *(const float4*)&wr[j];
            float4 cc = *(const float4*)&cv[j];
            a += w.x * cc.x + w.y * cc.y + w.z * cc.z + w.w * cc.w;
        }
        a += __shfl_down(a, 4);
        a += __shfl_down(a, 2);
        a += __shfl_down(a, 1);
        if (p == 0) out[((size_t)b * TT + t) * VOCAB + o] = a + bfc[o];
    }
}

extern "C" void kernel_launch(void* const* d_in, const int* in_sizes, int n_in,
                              void* d_out, int out_size, void* d_ws, size_t ws_size,
                              hipStream_t stream)
{
    (void)in_sizes; (void)n_in; (void)out_size; (void)ws_size;
    const int*   x     = (const int*)d_in[0];
    const float* embed = (const float*)d_in[1];
    const float* Wih0  = (const float*)d_in[2];
    const float* bih0  = (const float*)d_in[3];
    const float* Whh0  = (const float*)d_in[4];
    const float* bhh0  = (const float*)d_in[5];
    const float* Wih1  = (const float*)d_in[6];
    const float* bih1  = (const float*)d_in[7];
    const float* Whh1  = (const float*)d_in[8];
    const float* bhh1  = (const float*)d_in[9];
    const float* Wq    = (const float*)d_in[10];
    const float* Wk    = (const float*)d_in[11];
    const float* vvec  = (const float*)d_in[12];
    const float* Wfc   = (const float*)d_in[13];
    const float* bfc   = (const float*)d_in[14];
    float* out = (float*)d_out;
    float* ws  = (float*)d_ws;

    const size_t SZ = (size_t)TT * BATCH * HID;  // 524288 floats = 2 MB
    float* C0 = ws;            // reused as C1
    float* H0 = ws + SZ;       // reused as q
    float* Hs = ws + 2 * SZ;
    float* kb = ws + 3 * SZ;

    pre0_kernel<<<256, 256, 0, stream>>>(x, embed, Wih0, bih0, bhh0, C0);
    rec_kernel<<<8, 512, 0, stream>>>(Whh0, C0, H0);
    gemm256_kernel<<<256, 256, 0, stream>>>(H0, Wih1, bih1, bhh1, C0, 1);
    rec_kernel<<<8, 512, 0, stream>>>(Whh1, C0, Hs);
    gemm256_kernel<<<256, 256, 0, stream>>>(Hs, Wq, nullptr, nullptr, H0, 0);
    gemm256_kernel<<<256, 256, 0, stream>>>(Hs, Wk, nullptr, nullptr, kb, 0);
    attn_kernel<<<2048, 256, 0, stream>>>(H0, kb, vvec, Hs, Wfc, bfc, out);
}

// Round 2
// 446.649 us; speedup vs baseline: 1.2374x; 1.2374x over previous
//
#include <hip/hip_runtime.h>

#define HID   256
#define BATCH 8
#define TT    256   // time steps (SEQ-1)
#define SEQL  257
#define VOCAB 29
#define EMB   64
#define TG    4     // attn t-tile

typedef _Float16 f16;
typedef f16  f16x8 __attribute__((ext_vector_type(8)));
typedef float f32x4 __attribute__((ext_vector_type(4)));

__device__ __forceinline__ float fast_tanh(float x) {
    float e = exp2f(x * 2.8853900817779268f);
    return 1.0f - 2.0f * __builtin_amdgcn_rcpf(1.0f + e);
}

// C0[t][b][i] = emb[x[b][t]] . W_ih0[i] + b_ih0[i] + b_hh0[i]
__global__ __launch_bounds__(256) void pre0_kernel(
    const int* __restrict__ x, const float* __restrict__ embed,
    const float* __restrict__ Wih0, const float* __restrict__ bih0,
    const float* __restrict__ bhh0, float* __restrict__ C0)
{
    int b  = blockIdx.x & 7;
    int t0 = (blockIdx.x >> 3) * 8;
    int tid = threadIdx.x;
    __shared__ float er[8][EMB];
    for (int idx = tid; idx < 8 * EMB; idx += 256) {
        int tt = idx >> 6, j = idx & 63;
        er[tt][j] = embed[x[b * SEQL + t0 + tt] * EMB + j];
    }
    __syncthreads();
    int i = tid;
    float base = bih0[i] + bhh0[i];
    float acc[8];
#pragma unroll
    for (int tt = 0; tt < 8; ++tt) acc[tt] = base;
    const float* wr = Wih0 + i * EMB;
    for (int j = 0; j < EMB; j += 4) {
        float4 w = *(const float4*)&wr[j];
#pragma unroll
        for (int tt = 0; tt < 8; ++tt) {
            float4 h = *(const float4*)&er[tt][j];
            acc[tt] += h.x * w.x + h.y * w.y + h.z * w.z + h.w * w.w;
        }
    }
#pragma unroll
    for (int tt = 0; tt < 8; ++tt)
        C0[((t0 + tt) * BATCH + b) * HID + i] = acc[tt];
}

// Persistent-weight recurrence: h_t = tanh(C[t] + W * h_{t-1}), one WG per batch.
__global__ __launch_bounds__(512) void rec_kernel(
    const float* __restrict__ W,     // [HID][HID], out[n] = sum_k h[k]*W[n][k]
    const float* __restrict__ C,     // [t][b][i]
    float* __restrict__ Hout)        // [b][t][i]
{
    int b = blockIdx.x;
    int tid = threadIdx.x;
    int wave = tid >> 6, lane = tid & 63;
    int lrow = lane & 15, lkg = lane >> 4;
    __shared__ f16 hbuf[2][HID];
    for (int idx = tid; idx < 2 * HID; idx += 512) ((f16*)hbuf)[idx] = (f16)0.f;

    // B-frag: lane holds B[k = kt*32 + lkg*8 + e][n = wave*32 + ct*16 + lrow] = W[n][k]
    f16x8 bf[8][2];
#pragma unroll
    for (int kt = 0; kt < 8; ++kt)
#pragma unroll
        for (int ct = 0; ct < 2; ++ct) {
            int n = wave * 32 + ct * 16 + lrow;
            const float* src = W + n * HID + kt * 32 + lkg * 8;
            f16x8 v;
#pragma unroll
            for (int e = 0; e < 8; ++e) v[e] = (f16)src[e];
            bf[kt][ct] = v;
        }
    __syncthreads();

    int i0 = wave * 32 + lrow, i1 = i0 + 16;
    // prefetch C[0]
    float c0 = C[(0 * BATCH + b) * HID + i0];
    float c1 = C[(0 * BATCH + b) * HID + i1];

    int cur = 0;
    for (int t = 0; t < TT; ++t) {
        // prefetch next step's C while MFMAs run
        int tn = (t + 1 < TT) ? t + 1 : t;
        float cn0 = C[(tn * BATCH + b) * HID + i0];
        float cn1 = C[(tn * BATCH + b) * HID + i1];

        f32x4 a0a = {0.f,0.f,0.f,0.f}, a0b = {0.f,0.f,0.f,0.f};
        f32x4 a1a = {0.f,0.f,0.f,0.f}, a1b = {0.f,0.f,0.f,0.f};
#pragma unroll
        for (int kt = 0; kt < 8; kt += 2) {
            f16x8 aA, aB;
#pragma unroll
            for (int e = 0; e < 8; ++e) { aA[e] = (f16)0.f; aB[e] = (f16)0.f; }
            if (lrow == 0) {
                aA = *(const f16x8*)&hbuf[cur][kt * 32 + lkg * 8];
                aB = *(const f16x8*)&hbuf[cur][(kt + 1) * 32 + lkg * 8];
            }
            a0a = __builtin_amdgcn_mfma_f32_16x16x32_f16(aA, bf[kt][0],     a0a, 0, 0, 0);
            a1a = __builtin_amdgcn_mfma_f32_16x16x32_f16(aA, bf[kt][1],     a1a, 0, 0, 0);
            a0b = __builtin_amdgcn_mfma_f32_16x16x32_f16(aB, bf[kt + 1][0], a0b, 0, 0, 0);
            a1b = __builtin_amdgcn_mfma_f32_16x16x32_f16(aB, bf[kt + 1][1], a1b, 0, 0, 0);
        }
        int nxt = cur ^ 1;
        float v0 = fast_tanh(a0a[0] + a0b[0] + c0);
        float v1 = fast_tanh(a1a[0] + a1b[0] + c1);
        if (lane < 16) {
            hbuf[nxt][i0] = (f16)v0;
            hbuf[nxt][i1] = (f16)v1;
            float* ho = Hout + ((size_t)b * TT + t) * HID;
            ho[i0] = v0;
            ho[i1] = v1;
        }
        c0 = cn0; c1 = cn1;
        cur = nxt;
        // LDS-only barrier: do NOT drain vmcnt (global stores/loads keep flying)
        asm volatile("s_waitcnt lgkmcnt(0)\n\ts_barrier" ::: "memory");
    }
}

// Out[...] = In[b][t][:] . W[i][:] (+bias0[i]+bias1[i]); K = 256
__global__ __launch_bounds__(256) void gemm256_kernel(
    const float* __restrict__ In, const float* __restrict__ W,
    const float* __restrict__ bias0, const float* __restrict__ bias1,
    float* __restrict__ Out, int tmajor)
{
    int b  = blockIdx.x & 7;
    int t0 = (blockIdx.x >> 3) * 8;
    int tid = threadIdx.x;
    __shared__ float hs[8][HID];
    for (int idx = tid; idx < 8 * HID; idx += 256) {
        int tt = idx >> 8, j = idx & 255;
        hs[tt][j] = In[((size_t)b * TT + t0 + tt) * HID + j];
    }
    __syncthreads();
    int i = tid;
    float base = 0.f;
    if (bias0) base += bias0[i];
    if (bias1) base += bias1[i];
    float acc[8];
#pragma unroll
    for (int tt = 0; tt < 8; ++tt) acc[tt] = base;
    const float* wr = W + i * HID;
    for (int j = 0; j < HID; j += 4) {
        float4 w = *(const float4*)&wr[j];
#pragma unroll
        for (int tt = 0; tt < 8; ++tt) {
            float4 h = *(const float4*)&hs[tt][j];
            acc[tt] += h.x * w.x + h.y * w.y + h.z * w.z + h.w * w.w;
        }
    }
#pragma unroll
    for (int tt = 0; tt < 8; ++tt) {
        int t = t0 + tt;
        size_t o = tmajor ? ((size_t)(t * BATCH + b) * HID + i)
                          : (((size_t)b * TT + t) * HID + i);
        Out[o] = acc[tt];
    }
}

// Per (b, t-tile of TG): scores, softmax, ctx, fused FC. k/Hs rows read once per tile.
__global__ __launch_bounds__(256) void attn_kernel(
    const float* __restrict__ q, const float* __restrict__ k,
    const float* __restrict__ vvec, const float* __restrict__ Hs,
    const float* __restrict__ Wfc, const float* __restrict__ bfc,
    float* __restrict__ out)
{
    int b  = blockIdx.x >> 6;
    int t0 = (blockIdx.x & 63) * TG;
    int tid = threadIdx.x;
    int wave = tid >> 6, lane = tid & 63;
    __shared__ float qs[TG][HID], vs[HID], alpha[TG][HID], cvec[TG][2 * HID];
    __shared__ float redm[4][TG], reds[4][TG];
#pragma unroll
    for (int j = 0; j < TG; ++j)
        qs[j][tid] = q[((size_t)b * TT + t0 + j) * HID + tid];
    vs[tid] = vvec[tid];
    __syncthreads();

    // scores: thread = source position s = tid; 4 target rows share the k-row read
    float sc[TG];
#pragma unroll
    for (int j = 0; j < TG; ++j) sc[j] = -1e30f;
    {
        const float* kr = k + ((size_t)b * TT + tid) * HID;
        float a0 = 0.f, a1 = 0.f, a2 = 0.f, a3 = 0.f;
        for (int jj = 0; jj < HID; jj += 4) {
            float4 kv = *(const float4*)&kr[jj];
            float4 vv = *(const float4*)&vs[jj];
            float4 q0 = *(const float4*)&qs[0][jj];
            float4 q1 = *(const float4*)&qs[1][jj];
            float4 q2 = *(const float4*)&qs[2][jj];
            float4 q3 = *(const float4*)&qs[3][jj];
            a0 += vv.x * fast_tanh(q0.x + kv.x) + vv.y * fast_tanh(q0.y + kv.y)
                + vv.z * fast_tanh(q0.z + kv.z) + vv.w * fast_tanh(q0.w + kv.w);
            a1 += vv.x * fast_tanh(q1.x + kv.x) + vv.y * fast_tanh(q1.y + kv.y)
                + vv.z * fast_tanh(q1.z + kv.z) + vv.w * fast_tanh(q1.w + kv.w);
            a2 += vv.x * fast_tanh(q2.x + kv.x) + vv.y * fast_tanh(q2.y + kv.y)
                + vv.z * fast_tanh(q2.z + kv.z) + vv.w * fast_tanh(q2.w + kv.w);
            a3 += vv.x * fast_tanh(q3.x + kv.x) + vv.y * fast_tanh(q3.y + kv.y)
                + vv.z * fast_tanh(q3.z + kv.z) + vv.w * fast_tanh(q3.w + kv.w);
        }
        if (tid < t0 + 0) sc[0] = a0;
        if (tid < t0 + 1) sc[1] = a1;
        if (tid < t0 + 2) sc[2] = a2;
        if (tid < t0 + 3) sc[3] = a3;
    }
    // 4 interleaved block-max reductions
    float m0 = sc[0], m1 = sc[1], m2 = sc[2], m3 = sc[3];
#pragma unroll
    for (int off = 32; off; off >>= 1) {
        m0 = fmaxf(m0, __shfl_down(m0, off));
        m1 = fmaxf(m1, __shfl_down(m1, off));
        m2 = fmaxf(m2, __shfl_down(m2, off));
        m3 = fmaxf(m3, __shfl_down(m3, off));
    }
    if (lane == 0) { redm[wave][0] = m0; redm[wave][1] = m1; redm[wave][2] = m2; redm[wave][3] = m3; }
    __syncthreads();
    float mj[TG], ej[TG];
#pragma unroll
    for (int j = 0; j < TG; ++j) {
        float m = fmaxf(fmaxf(redm[0][j], redm[1][j]), fmaxf(redm[2][j], redm[3][j]));
        mj[j] = m;
        ej[j] = (tid < t0 + j) ? exp2f((sc[j] - m) * 1.4426950408889634f) : 0.f;
    }
    float z0 = ej[0], z1 = ej[1], z2 = ej[2], z3 = ej[3];
#pragma unroll
    for (int off = 32; off; off >>= 1) {
        z0 += __shfl_down(z0, off);
        z1 += __shfl_down(z1, off);
        z2 += __shfl_down(z2, off);
        z3 += __shfl_down(z3, off);
    }
    if (lane == 0) { reds[wave][0] = z0; reds[wave][1] = z1; reds[wave][2] = z2; reds[wave][3] = z3; }
    __syncthreads();
#pragma unroll
    for (int j = 0; j < TG; ++j) {
        float z = reds[0][j] + reds[1][j] + reds[2][j] + reds[3][j];
        alpha[j][tid] = (t0 + j == 0) ? 0.f : ej[j] * __builtin_amdgcn_rcpf(z);
    }
    __syncthreads();

    // ctx: thread = hidden dim i = tid; Hs rows read once for all 4 rows
    float c0 = 0.f, c1 = 0.f, c2 = 0.f, c3 = 0.f;
    const float* hb = Hs + (size_t)b * TT * HID;
    for (int s = 0; s < t0 + TG; s += 4) {
        float4 av0 = *(const float4*)&alpha[0][s];
        float4 av1 = *(const float4*)&alpha[1][s];
        float4 av2 = *(const float4*)&alpha[2][s];
        float4 av3 = *(const float4*)&alpha[3][s];
        float h0 = hb[(s + 0) * HID + tid];
        float h1 = hb[(s + 1) * HID + tid];
        float h2 = hb[(s + 2) * HID + tid];
        float h3 = hb[(s + 3) * HID + tid];
        c0 += av0.x * h0 + av0.y * h1 + av0.z * h2 + av0.w * h3;
        c1 += av1.x * h0 + av1.y * h1 + av1.z * h2 + av1.w * h3;
        c2 += av2.x * h0 + av2.y * h1 + av2.z * h2 + av2.w * h3;
        c3 += av3.x * h0 + av3.y * h1 + av3.z * h2 + av3.w * h3;
    }
    cvec[0][tid] = hb[(size_t)(t0 + 0) * HID + tid]; cvec[0][HID + tid] = c0;
    cvec[1][tid] = hb[(size_t)(t0 + 1) * HID + tid]; cvec[1][HID + tid] = c1;
    cvec[2][tid] = hb[(size_t)(t0 + 2) * HID + tid]; cvec[2][HID + tid] = c2;
    cvec[3][tid] = hb[(size_t)(t0 + 3) * HID + tid]; cvec[3][HID + tid] = c3;
    __syncthreads();

    if (tid < VOCAB * 8) {
        int o = tid >> 3, p = tid & 7;
        const float* wr = Wfc + o * 2 * HID + p * 64;
#pragma unroll
        for (int j = 0; j < TG; ++j) {
            const float* cv = &cvec[j][p * 64];
            float a = 0.f;
            for (int jj = 0; jj < 64; jj += 4) {
                float4 w  = *(const float4*)&wr[jj];
                float4 cc = *(const float4*)&cv[jj];
                a += w.x * cc.x + w.y * cc.y + w.z * cc.z + w.w * cc.w;
            }
            a += __shfl_down(a, 4);
            a += __shfl_down(a, 2);
            a += __shfl_down(a, 1);
            if (p == 0) out[((size_t)b * TT + t0 + j) * VOCAB + o] = a + bfc[o];
        }
    }
}

extern "C" void kernel_launch(void* const* d_in, const int* in_sizes, int n_in,
                              void* d_out, int out_size, void* d_ws, size_t ws_size,
                              hipStream_t stream)
{
    (void)in_sizes; (void)n_in; (void)out_size; (void)ws_size;
    const int*   x     = (const int*)d_in[0];
    const float* embed = (const float*)d_in[1];
    const float* Wih0  = (const float*)d_in[2];
    const float* bih0  = (const float*)d_in[3];
    const float* Whh0  = (const float*)d_in[4];
    const float* bhh0  = (const float*)d_in[5];
    const float* Wih1  = (const float*)d_in[6];
    const float* bih1  = (const float*)d_in[7];
    const float* Whh1  = (const float*)d_in[8];
    const float* bhh1  = (const float*)d_in[9];
    const float* Wq    = (const float*)d_in[10];
    const float* Wk    = (const float*)d_in[11];
    const float* vvec  = (const float*)d_in[12];
    const float* Wfc   = (const float*)d_in[13];
    const float* bfc   = (const float*)d_in[14];
    float* out = (float*)d_out;
    float* ws  = (float*)d_ws;

    const size_t SZ = (size_t)TT * BATCH * HID;  // 524288 floats = 2 MB
    float* C0 = ws;            // reused as C1
    float* H0 = ws + SZ;       // reused as q
    float* Hs = ws + 2 * SZ;
    float* kb = ws + 3 * SZ;

    pre0_kernel<<<256, 256, 0, stream>>>(x, embed, Wih0, bih0, bhh0, C0);
    rec_kernel<<<8, 512, 0, stream>>>(Whh0, C0, H0);
    gemm256_kernel<<<256, 256, 0, stream>>>(H0, Wih1, bih1, bhh1, C0, 1);
    rec_kernel<<<8, 512, 0, stream>>>(Whh1, C0, Hs);
    gemm256_kernel<<<256, 256, 0, stream>>>(Hs, Wq, nullptr, nullptr, H0, 0);
    gemm256_kernel<<<256, 256, 0, stream>>>(Hs, Wk, nullptr, nullptr, kb, 0);
    attn_kernel<<<512, 256, 0, stream>>>(H0, kb, vvec, Hs, Wfc, bfc, out);
}

// Round 3
// 358.628 us; speedup vs baseline: 1.5412x; 1.2454x over previous
//
#include <hip/hip_runtime.h>

#define HID   256
#define BATCH 8
#define TT    256   // time steps (SEQ-1)
#define SEQL  257
#define VOCAB 29
#define EMB   64
#define TG    4     // attn t-tile

typedef _Float16 f16;
typedef f16  f16x8 __attribute__((ext_vector_type(8)));
typedef float f32x4 __attribute__((ext_vector_type(4)));

__device__ __forceinline__ float fast_tanh(float x) {
    float e = exp2f(x * 2.8853900817779268f);
    return 1.0f - 2.0f * __builtin_amdgcn_rcpf(1.0f + e);
}

// C0[t][b][i] = emb[x[b][t]] . W_ih0[i] + b_ih0[i] + b_hh0[i]
__global__ __launch_bounds__(256) void pre0_kernel(
    const int* __restrict__ x, const float* __restrict__ embed,
    const float* __restrict__ Wih0, const float* __restrict__ bih0,
    const float* __restrict__ bhh0, float* __restrict__ C0)
{
    int b  = blockIdx.x & 7;
    int t0 = (blockIdx.x >> 3) * 8;
    int tid = threadIdx.x;
    __shared__ float er[8][EMB];
    for (int idx = tid; idx < 8 * EMB; idx += 256) {
        int tt = idx >> 6, j = idx & 63;
        er[tt][j] = embed[x[b * SEQL + t0 + tt] * EMB + j];
    }
    __syncthreads();
    int i = tid;
    float base = bih0[i] + bhh0[i];
    float acc[8];
#pragma unroll
    for (int tt = 0; tt < 8; ++tt) acc[tt] = base;
    const float* wr = Wih0 + i * EMB;
    for (int j = 0; j < EMB; j += 4) {
        float4 w = *(const float4*)&wr[j];
#pragma unroll
        for (int tt = 0; tt < 8; ++tt) {
            float4 h = *(const float4*)&er[tt][j];
            acc[tt] += h.x * w.x + h.y * w.y + h.z * w.z + h.w * w.w;
        }
    }
#pragma unroll
    for (int tt = 0; tt < 8; ++tt)
        C0[((t0 + tt) * BATCH + b) * HID + i] = acc[tt];
}

// Persistent-weight recurrence: h_t = tanh(C[t] + W * h_{t-1}), one WG per batch.
__global__ __launch_bounds__(512) void rec_kernel(
    const float* __restrict__ W,     // [HID][HID], out[n] = sum_k h[k]*W[n][k]
    const float* __restrict__ C,     // [t][b][i]
    float* __restrict__ Hout)        // [b][t][i]
{
    int b = blockIdx.x;
    int tid = threadIdx.x;
    int wave = tid >> 6, lane = tid & 63;
    int lrow = lane & 15, lkg = lane >> 4;
    __shared__ f16 hbuf[2][HID];
    for (int idx = tid; idx < 2 * HID; idx += 512) ((f16*)hbuf)[idx] = (f16)0.f;

    // B-frag: lane holds B[k = kt*32 + lkg*8 + e][n = wave*32 + ct*16 + lrow] = W[n][k]
    f16x8 bf[8][2];
#pragma unroll
    for (int kt = 0; kt < 8; ++kt)
#pragma unroll
        for (int ct = 0; ct < 2; ++ct) {
            int n = wave * 32 + ct * 16 + lrow;
            const float* src = W + n * HID + kt * 32 + lkg * 8;
            f16x8 v;
#pragma unroll
            for (int e = 0; e < 8; ++e) v[e] = (f16)src[e];
            bf[kt][ct] = v;
        }
    __syncthreads();

    int i0 = wave * 32 + lrow, i1 = i0 + 16;
    const float* cp = C + b * HID;
    float c0 = cp[i0], c1 = cp[i1];
    cp += BATCH * HID;
    float* ho = Hout + (size_t)b * TT * HID;

    // Persistent A-fragments: zero once; masked ds_read writes only lrow==0 lanes,
    // all other lanes stay zero for the whole loop (M=1 rows 1..15 of A).
    f16x8 a[8];
#pragma unroll
    for (int kt = 0; kt < 8; ++kt)
#pragma unroll
        for (int e = 0; e < 8; ++e) a[kt][e] = (f16)0.f;
    const f32x4 Z = {0.f, 0.f, 0.f, 0.f};  // persistent zero C-operand

    int cur = 0;
    for (int t = 0; t < TT; ++t) {
        // prefetch next step's C (last iteration reads harmless garbage, unused)
        float cn0 = cp[i0];
        float cn1 = cp[i1];
        cp += BATCH * HID;

        if (lrow == 0) {
#pragma unroll
            for (int kt = 0; kt < 8; ++kt)
                a[kt] = *(const f16x8*)&hbuf[cur][kt * 32 + lkg * 8];
        }
        // 8 independent chains of depth 2
        f32x4 p00 = __builtin_amdgcn_mfma_f32_16x16x32_f16(a[0], bf[0][0], Z, 0, 0, 0);
        f32x4 p01 = __builtin_amdgcn_mfma_f32_16x16x32_f16(a[0], bf[0][1], Z, 0, 0, 0);
        f32x4 p10 = __builtin_amdgcn_mfma_f32_16x16x32_f16(a[2], bf[2][0], Z, 0, 0, 0);
        f32x4 p11 = __builtin_amdgcn_mfma_f32_16x16x32_f16(a[2], bf[2][1], Z, 0, 0, 0);
        f32x4 p20 = __builtin_amdgcn_mfma_f32_16x16x32_f16(a[4], bf[4][0], Z, 0, 0, 0);
        f32x4 p21 = __builtin_amdgcn_mfma_f32_16x16x32_f16(a[4], bf[4][1], Z, 0, 0, 0);
        f32x4 p30 = __builtin_amdgcn_mfma_f32_16x16x32_f16(a[6], bf[6][0], Z, 0, 0, 0);
        f32x4 p31 = __builtin_amdgcn_mfma_f32_16x16x32_f16(a[6], bf[6][1], Z, 0, 0, 0);
        p00 = __builtin_amdgcn_mfma_f32_16x16x32_f16(a[1], bf[1][0], p00, 0, 0, 0);
        p01 = __builtin_amdgcn_mfma_f32_16x16x32_f16(a[1], bf[1][1], p01, 0, 0, 0);
        p10 = __builtin_amdgcn_mfma_f32_16x16x32_f16(a[3], bf[3][0], p10, 0, 0, 0);
        p11 = __builtin_amdgcn_mfma_f32_16x16x32_f16(a[3], bf[3][1], p11, 0, 0, 0);
        p20 = __builtin_amdgcn_mfma_f32_16x16x32_f16(a[5], bf[5][0], p20, 0, 0, 0);
        p21 = __builtin_amdgcn_mfma_f32_16x16x32_f16(a[5], bf[5][1], p21, 0, 0, 0);
        p30 = __builtin_amdgcn_mfma_f32_16x16x32_f16(a[7], bf[7][0], p30, 0, 0, 0);
        p31 = __builtin_amdgcn_mfma_f32_16x16x32_f16(a[7], bf[7][1], p31, 0, 0, 0);

        int nxt = cur ^ 1;
        float v0 = fast_tanh(((p00[0] + p10[0]) + (p20[0] + p30[0])) + c0);
        float v1 = fast_tanh(((p01[0] + p11[0]) + (p21[0] + p31[0])) + c1);
        if (lane < 16) {
            hbuf[nxt][i0] = (f16)v0;
            hbuf[nxt][i1] = (f16)v1;
            ho[i0] = v0;
            ho[i1] = v1;
        }
        ho += HID;
        c0 = cn0; c1 = cn1;
        cur = nxt;
        // LDS-only barrier: global stores/loads keep flying
        asm volatile("s_waitcnt lgkmcnt(0)\n\ts_barrier" ::: "memory");
    }
}

// Out[...] = In[b][t][:] . W[i][:] (+bias0[i]+bias1[i]); K = 256; optional tanh
__global__ __launch_bounds__(256) void gemm256_kernel(
    const float* __restrict__ In, const float* __restrict__ W,
    const float* __restrict__ bias0, const float* __restrict__ bias1,
    float* __restrict__ Out, int tmajor, int dotanh)
{
    int b  = blockIdx.x & 7;
    int t0 = (blockIdx.x >> 3) * 8;
    int tid = threadIdx.x;
    __shared__ float hs[8][HID];
    for (int idx = tid; idx < 8 * HID; idx += 256) {
        int tt = idx >> 8, j = idx & 255;
        hs[tt][j] = In[((size_t)b * TT + t0 + tt) * HID + j];
    }
    __syncthreads();
    int i = tid;
    float base = 0.f;
    if (bias0) base += bias0[i];
    if (bias1) base += bias1[i];
    float acc[8];
#pragma unroll
    for (int tt = 0; tt < 8; ++tt) acc[tt] = base;
    const float* wr = W + i * HID;
    for (int j = 0; j < HID; j += 4) {
        float4 w = *(const float4*)&wr[j];
#pragma unroll
        for (int tt = 0; tt < 8; ++tt) {
            float4 h = *(const float4*)&hs[tt][j];
            acc[tt] += h.x * w.x + h.y * w.y + h.z * w.z + h.w * w.w;
        }
    }
#pragma unroll
    for (int tt = 0; tt < 8; ++tt) {
        int t = t0 + tt;
        float v = dotanh ? fast_tanh(acc[tt]) : acc[tt];
        size_t o = tmajor ? ((size_t)(t * BATCH + b) * HID + i)
                          : (((size_t)b * TT + t) * HID + i);
        Out[o] = v;
    }
}

// Per (b, t-tile of TG): scores via tanh addition identity on precomputed
// tq=tanh(q), tk=tanh(k):  tanh(q+k) = (tq+tk)/(1+tq*tk).
__global__ __launch_bounds__(256) void attn_kernel(
    const float* __restrict__ tq, const float* __restrict__ tk,
    const float* __restrict__ vvec, const float* __restrict__ Hs,
    const float* __restrict__ Wfc, const float* __restrict__ bfc,
    float* __restrict__ out)
{
    int b  = blockIdx.x >> 6;
    int t0 = (blockIdx.x & 63) * TG;
    int tid = threadIdx.x;
    int wave = tid >> 6, lane = tid & 63;
    __shared__ float qs[TG][HID], vs[HID], alpha[TG][HID], cvec[TG][2 * HID];
    __shared__ float redm[4][TG], reds[4][TG];
#pragma unroll
    for (int j = 0; j < TG; ++j)
        qs[j][tid] = tq[((size_t)b * TT + t0 + j) * HID + tid];
    vs[tid] = vvec[tid];
    __syncthreads();

    float sc[TG];
#pragma unroll
    for (int j = 0; j < TG; ++j) sc[j] = -1e30f;
    if ((wave << 6) < t0 + TG) {   // causality: whole-wave skip for s >= t0+TG
        const float* kr = tk + ((size_t)b * TT + tid) * HID;
        float a0 = 0.f, a1 = 0.f, a2 = 0.f, a3 = 0.f;
        for (int jj = 0; jj < HID; jj += 4) {
            float4 kv = *(const float4*)&kr[jj];
            float4 vv = *(const float4*)&vs[jj];
            float4 q0 = *(const float4*)&qs[0][jj];
            float4 q1 = *(const float4*)&qs[1][jj];
            float4 q2 = *(const float4*)&qs[2][jj];
            float4 q3 = *(const float4*)&qs[3][jj];
#define TADD(qc, kc, vc, acc) { float num = qc + kc; float den = __builtin_fmaf(qc, kc, 1.f); acc += vc * num * __builtin_amdgcn_rcpf(den); }
            TADD(q0.x, kv.x, vv.x, a0) TADD(q0.y, kv.y, vv.y, a0) TADD(q0.z, kv.z, vv.z, a0) TADD(q0.w, kv.w, vv.w, a0)
            TADD(q1.x, kv.x, vv.x, a1) TADD(q1.y, kv.y, vv.y, a1) TADD(q1.z, kv.z, vv.z, a1) TADD(q1.w, kv.w, vv.w, a1)
            TADD(q2.x, kv.x, vv.x, a2) TADD(q2.y, kv.y, vv.y, a2) TADD(q2.z, kv.z, vv.z, a2) TADD(q2.w, kv.w, vv.w, a2)
            TADD(q3.x, kv.x, vv.x, a3) TADD(q3.y, kv.y, vv.y, a3) TADD(q3.z, kv.z, vv.z, a3) TADD(q3.w, kv.w, vv.w, a3)
#undef TADD
        }
        if (tid < t0 + 0) sc[0] = a0;
        if (tid < t0 + 1) sc[1] = a1;
        if (tid < t0 + 2) sc[2] = a2;
        if (tid < t0 + 3) sc[3] = a3;
    }
    float m0 = sc[0], m1 = sc[1], m2 = sc[2], m3 = sc[3];
#pragma unroll
    for (int off = 32; off; off >>= 1) {
        m0 = fmaxf(m0, __shfl_down(m0, off));
        m1 = fmaxf(m1, __shfl_down(m1, off));
        m2 = fmaxf(m2, __shfl_down(m2, off));
        m3 = fmaxf(m3, __shfl_down(m3, off));
    }
    if (lane == 0) { redm[wave][0] = m0; redm[wave][1] = m1; redm[wave][2] = m2; redm[wave][3] = m3; }
    __syncthreads();
    float ej[TG];
#pragma unroll
    for (int j = 0; j < TG; ++j) {
        float m = fmaxf(fmaxf(redm[0][j], redm[1][j]), fmaxf(redm[2][j], redm[3][j]));
        ej[j] = (tid < t0 + j) ? exp2f((sc[j] - m) * 1.4426950408889634f) : 0.f;
    }
    float z0 = ej[0], z1 = ej[1], z2 = ej[2], z3 = ej[3];
#pragma unroll
    for (int off = 32; off; off >>= 1) {
        z0 += __shfl_down(z0, off);
        z1 += __shfl_down(z1, off);
        z2 += __shfl_down(z2, off);
        z3 += __shfl_down(z3, off);
    }
    if (lane == 0) { reds[wave][0] = z0; reds[wave][1] = z1; reds[wave][2] = z2; reds[wave][3] = z3; }
    __syncthreads();
#pragma unroll
    for (int j = 0; j < TG; ++j) {
        float z = reds[0][j] + reds[1][j] + reds[2][j] + reds[3][j];
        alpha[j][tid] = (t0 + j == 0) ? 0.f : ej[j] * __builtin_amdgcn_rcpf(z);
    }
    __syncthreads();

    float c0 = 0.f, c1 = 0.f, c2 = 0.f, c3 = 0.f;
    const float* hb = Hs + (size_t)b * TT * HID;
    for (int s = 0; s < t0 + TG; s += 4) {
        float4 av0 = *(const float4*)&alpha[0][s];
        float4 av1 = *(const float4*)&alpha[1][s];
        float4 av2 = *(const float4*)&alpha[2][s];
        float4 av3 = *(const float4*)&alpha[3][s];
        float h0 = hb[(s + 0) * HID + tid];
        float h1 = hb[(s + 1) * HID + tid];
        float h2 = hb[(s + 2) * HID + tid];
        float h3 = hb[(s + 3) * HID + tid];
        c0 += av0.x * h0 + av0.y * h1 + av0.z * h2 + av0.w * h3;
        c1 += av1.x * h0 + av1.y * h1 + av1.z * h2 + av1.w * h3;
        c2 += av2.x * h0 + av2.y * h1 + av2.z * h2 + av2.w * h3;
        c3 += av3.x * h0 + av3.y * h1 + av3.z * h2 + av3.w * h3;
    }
    cvec[0][tid] = hb[(size_t)(t0 + 0) * HID + tid]; cvec[0][HID + tid] = c0;
    cvec[1][tid] = hb[(size_t)(t0 + 1) * HID + tid]; cvec[1][HID + tid] = c1;
    cvec[2][tid] = hb[(size_t)(t0 + 2) * HID + tid]; cvec[2][HID + tid] = c2;
    cvec[3][tid] = hb[(size_t)(t0 + 3) * HID + tid]; cvec[3][HID + tid] = c3;
    __syncthreads();

    if (tid < VOCAB * 8) {
        int o = tid >> 3, p = tid & 7;
        const float* wr = Wfc + o * 2 * HID + p * 64;
#pragma unroll
        for (int j = 0; j < TG; ++j) {
            const float* cv = &cvec[j][p * 64];
            float a = 0.f;
            for (int jj = 0; jj < 64; jj += 4) {
                float4 w  = *(const float4*)&wr[jj];
                float4 cc = *(const float4*)&cv[jj];
                a += w.x * cc.x + w.y * cc.y + w.z * cc.z + w.w * cc.w;
            }
            a += __shfl_down(a, 4);
            a += __shfl_down(a, 2);
            a += __shfl_down(a, 1);
            if (p == 0) out[((size_t)b * TT + t0 + j) * VOCAB + o] = a + bfc[o];
        }
    }
}

extern "C" void kernel_launch(void* const* d_in, const int* in_sizes, int n_in,
                              void* d_out, int out_size, void* d_ws, size_t ws_size,
                              hipStream_t stream)
{
    (void)in_sizes; (void)n_in; (void)out_size; (void)ws_size;
    const int*   x     = (const int*)d_in[0];
    const float* embed = (const float*)d_in[1];
    const float* Wih0  = (const float*)d_in[2];
    const float* bih0  = (const float*)d_in[3];
    const float* Whh0  = (const float*)d_in[4];
    const float* bhh0  = (const float*)d_in[5];
    const float* Wih1  = (const float*)d_in[6];
    const float* bih1  = (const float*)d_in[7];
    const float* Whh1  = (const float*)d_in[8];
    const float* bhh1  = (const float*)d_in[9];
    const float* Wq    = (const float*)d_in[10];
    const float* Wk    = (const float*)d_in[11];
    const float* vvec  = (const float*)d_in[12];
    const float* Wfc   = (const float*)d_in[13];
    const float* bfc   = (const float*)d_in[14];
    float* out = (float*)d_out;
    float* ws  = (float*)d_ws;

    const size_t SZ = (size_t)TT * BATCH * HID;  // 524288 floats = 2 MB
    float* C0 = ws;            // reused as C1
    float* H0 = ws + SZ;       // reused as tq
    float* Hs = ws + 2 * SZ;
    float* kb = ws + 3 * SZ;

    pre0_kernel<<<256, 256, 0, stream>>>(x, embed, Wih0, bih0, bhh0, C0);
    rec_kernel<<<8, 512, 0, stream>>>(Whh0, C0, H0);
    gemm256_kernel<<<256, 256, 0, stream>>>(H0, Wih1, bih1, bhh1, C0, 1, 0);
    rec_kernel<<<8, 512, 0, stream>>>(Whh1, C0, Hs);
    gemm256_kernel<<<256, 256, 0, stream>>>(Hs, Wq, nullptr, nullptr, H0, 0, 1);
    gemm256_kernel<<<256, 256, 0, stream>>>(Hs, Wk, nullptr, nullptr, kb, 0, 1);
    attn_kernel<<<512, 256, 0, stream>>>(H0, kb, vvec, Hs, Wfc, bfc, out);
}